// Round 2
// baseline (4203.260 us; speedup 1.0000x reference)
//
#include <hip/hip_runtime.h>

// MPS forward, MI355X/gfx950.
// B=4096 S=256 F=32 D=64 O=16, LABEL=128.
// Strategy: per-site GEMM v' = (v (x) x) @ W  with K=(d,f)=2048, N=64 using
// mfma_f32_32x32x16_f16. A-operand synthesized in registers (outer product,
// v_pk_mul_f16), B-operand (W) pre-swizzled to MFMA fragment order in ws
// (fp16) so the K-loop reads it via coalesced 16B global loads.
// v2: 256 blocks x 1024 threads (16 waves = 4/SIMD), 32 rows/block, wave =
// (t = N-tile, kq = K-eighth); x double-buffered in LDS with reg prefetch.
// v3 (MLP rework): per-site W fragments burst-loaded into half8 wbuf[16]
// (16 wave-loads in flight per wave -> 256KB in flight per CU) issued at the
// TOP of the site iteration; main-loop barriers are raw s_barrier with
// lgkmcnt(0)-only drain so the W burst stays in flight across barrier 1 and
// the compiler emits counted vmcnt waits per wbuf use. All LDS prework
// (state preload, x-octet reads) hoisted before barrier 1 so the compute
// phase is pure VALU+MFMA+vmcnt. Label kernel g2-loop gets 8-deep bursts.

typedef _Float16 half2v __attribute__((ext_vector_type(2)));
typedef _Float16 half8 __attribute__((ext_vector_type(8)));
typedef float f32x16 __attribute__((ext_vector_type(16)));
typedef unsigned int uint4v __attribute__((ext_vector_type(4)));

#define MFMA32(a, b, c) __builtin_amdgcn_mfma_f32_32x32x16_f16((a), (b), (c), 0, 0, 0)

#define VPAD 66  // fp32 state row stride (64 + 2 pad: bank spread, b64-aligned)

// workspace byte offsets (total 72,613,888 bytes required)
#define WS_WLF 0L
#define WS_WRF 33292288L
#define WS_WLAB 66322432L
#define WS_V 70516736L
#define WS_R 71565312L

// raw barrier: drain LDS only — global loads stay in flight across it
#define LGKM_BARRIER()                                   \
  do {                                                   \
    asm volatile("s_waitcnt lgkmcnt(0)" ::: "memory");   \
    __builtin_amdgcn_s_barrier();                        \
  } while (0)

__device__ __forceinline__ f32x16 zero16() {
  f32x16 z;
#pragma unroll
  for (int i = 0; i < 16; ++i) z[i] = 0.0f;
  return z;
}

__device__ __forceinline__ unsigned int pack2h(float a, float b) {
  half2v h;
  h[0] = (_Float16)a;
  h[1] = (_Float16)b;
  return __builtin_bit_cast(unsigned int, h);
}

__device__ __forceinline__ half2v splat2(float a) {
  _Float16 x = (_Float16)a;
  half2v h;
  h[0] = x;
  h[1] = x;
  return h;
}

// A-fragment synth: splat-scalar * f16-octet (4x v_pk_mul_f16)
__device__ __forceinline__ half8 mulfrag(const half2v s, const unsigned int* o) {
  uint4v t;
#pragma unroll
  for (int i = 0; i < 4; ++i) {
    half2v b = __builtin_bit_cast(half2v, o[i]);
    half2v p = s * b;
    t[i] = __builtin_bit_cast(unsigned int, p);
  }
  return __builtin_bit_cast(half8, t);
}

// ---------------------------------------------------------------------------
// Prologue: convert W to fp16 in MFMA B-fragment order.
// Fragment id F = ((site*128 + s)*2 + t)*64 + lane  (chains)
//             F = (s*32 + t)*64 + lane              (label)
// value j of fragment: B[k = s*16 + (lane>>5)*8 + j][n = t*32 + (lane&31)]
// left/label: k=(d,f) -> d=k>>5, f=k&31 ; n=e (left) or n=(e*16+o) (label)
// right:      k=(f,e) -> f=k>>6, e=k&63 ; n=d
// ---------------------------------------------------------------------------
__global__ void prep_kernel(const float* __restrict__ wl, const float* __restrict__ wr,
                            const float* __restrict__ wlab,
                            _Float16* __restrict__ wlf, _Float16* __restrict__ wrf,
                            _Float16* __restrict__ wlabf) {
  const long t0 = (long)blockIdx.x * blockDim.x + threadIdx.x;
  const long stride = (long)gridDim.x * blockDim.x;
  const long NL = 127L * 128 * 2 * 64;
  const long NR = 126L * 128 * 2 * 64;
  const long NB = 128L * 32 * 64;

  for (long F = t0; F < NL; F += stride) {
    const int l = (int)(F & 63), t = (int)((F >> 6) & 1);
    const int s = (int)((F >> 7) & 127), site = (int)(F >> 14);
    const int k0 = s * 16 + ((l >> 5) << 3);
    const int d = k0 >> 5, f0 = k0 & 31, e = t * 32 + (l & 31);
    const float* src = wl + (((long)site * 64 + d) * 32 + f0) * 64 + e;
    half8 v;
#pragma unroll
    for (int j = 0; j < 8; ++j) v[j] = (_Float16)src[(long)j * 64];
    *(half8*)(wlf + F * 8) = v;
  }
  for (long F = t0; F < NR; F += stride) {
    const int l = (int)(F & 63), t = (int)((F >> 6) & 1);
    const int s = (int)((F >> 7) & 127), site = (int)(F >> 14);
    const int k0 = s * 16 + ((l >> 5) << 3);
    const int f = k0 >> 6, e0 = k0 & 63, d = t * 32 + (l & 31);
    const float* src = wr + (((long)site * 64 + d) * 32 + f) * 64 + e0;
    half8 v;
#pragma unroll
    for (int j = 0; j < 8; ++j) v[j] = (_Float16)src[j];
    *(half8*)(wrf + F * 8) = v;
  }
  for (long F = t0; F < NB; F += stride) {
    const int l = (int)(F & 63), t = (int)((F >> 6) & 31);
    const int s = (int)(F >> 11);
    const int k0 = s * 16 + ((l >> 5) << 3);
    const int d = k0 >> 5, f0 = k0 & 31;
    const int n = t * 32 + (l & 31);
    const int e = n >> 4, oo = n & 15;
    const float* src = wlab + (((long)d * 32 + f0) * 64 + e) * 16 + oo;
    half8 v;
#pragma unroll
    for (int j = 0; j < 8; ++j) v[j] = (_Float16)src[(long)j * 1024];
    *(half8*)(wlabf + F * 8) = v;
  }
}

// ---------------------------------------------------------------------------
// Chain kernel: blocks 0..127 = left chain, 128..255 = right chain; 32 rows
// each, 1024 threads = 16 waves (4/SIMD). Wave: t = w&1, kq = w>>1 (K-eighth).
// ---------------------------------------------------------------------------
__launch_bounds__(1024, 4)
__global__ void chain_kernel(const float* __restrict__ x, const float* __restrict__ w0,
                             const float* __restrict__ wlast,
                             const _Float16* __restrict__ wlf,
                             const _Float16* __restrict__ wrf,
                             float* __restrict__ wsV, float* __restrict__ wsR) {
  __shared__ float vacc[2][32 * VPAD];       // ping-pong fp32 state/accumulator
  __shared__ unsigned int xsf[2][2][64][4];  // left: x octets, dbuf x [parity][lane]
  __shared__ unsigned int xplu[2][32][17];   // right: packed f16 x scalars, dbuf
  __shared__ float xinit[32][33];            // fp32 x for init GEMM

  const int tid = threadIdx.x;
  const int lane = tid & 63;
  const int wv = tid >> 6;   // 0..15
  const int t = wv & 1;      // N-tile
  const int kq = wv >> 1;    // K-eighth 0..7
  const int m = lane & 31;   // batch row in tile / col in tile
  const int h = lane >> 5;   // half-wave
  const int chain = blockIdx.x >> 7;  // 0 = left(v), 1 = right(r)
  const int b0 = (blockIdx.x & 127) * 32;

  // ---- stage x edge column for init GEMM
  if (tid < 128) {
    const int row = tid >> 2, c8 = (tid & 3) * 8;
    const float* xp = x + ((long)(b0 + row) * 256 + (chain ? 255 : 0)) * 32 + c8;
    const float4 xa = ((const float4*)xp)[0];
    const float4 xb = ((const float4*)xp)[1];
    xinit[row][c8 + 0] = xa.x; xinit[row][c8 + 1] = xa.y;
    xinit[row][c8 + 2] = xa.z; xinit[row][c8 + 3] = xa.w;
    xinit[row][c8 + 4] = xb.x; xinit[row][c8 + 5] = xb.y;
    xinit[row][c8 + 6] = xb.z; xinit[row][c8 + 7] = xb.w;
  }
  __syncthreads();
  // ---- init state: v0 = x[:,0] @ W0   |   r0[d] = sum_f x[:,255][f]*Wlast[d][f]
  {
    const int row = tid >> 5, c = tid & 31;
    float a0 = 0.f, a1 = 0.f;
    if (chain == 0) {
#pragma unroll 8
      for (int f = 0; f < 32; ++f) {
        a0 += xinit[row][f] * w0[f * 64 + c];
        a1 += xinit[row][f] * w0[f * 64 + c + 32];
      }
    } else {
#pragma unroll 8
      for (int f = 0; f < 32; ++f) {
        a0 += xinit[row][f] * wlast[c * 32 + f];
        a1 += xinit[row][f] * wlast[(c + 32) * 32 + f];
      }
    }
    vacc[1][row * VPAD + c] = a0;
    vacc[1][row * VPAD + c + 32] = a1;
  }
  // ---- stage x for first site into buffer 0
  if (tid < 512) {
    const int row = tid >> 4, q = tid & 15;
    const float2 f2 = *(const float2*)(x + ((long)(b0 + row) * 256 + (chain ? 254 : 1)) * 32 + 2 * q);
    const unsigned int pk = pack2h(f2.x, f2.y);
    if (chain == 0)
      xsf[0][q >> 3][((q >> 2) & 1) * 32 + row][q & 3] = pk;
    else
      xplu[0][row][q] = pk;
  }
  __syncthreads();

  const int NIT = chain ? 126 : 127;

  for (int it = 0; it < NIT; ++it) {
    float* P = vacc[it & 1];               // this site's accumulator (zeroed below)
    const float* Q = vacc[(it + 1) & 1];   // previous state
    const int cb = it & 1, nb = (it & 1) ^ 1;

    // ======== W burst: 16 fragment loads issued first, stay in flight
    // across barrier1 (lgkm-only). Counted vmcnt waits at each use below.
    half8 wbuf[16];
    {
      const _Float16* wb = (chain == 0)
          ? (wlf + (long)it * 131072 + kq * 16384 + t * 512 + lane * 8)
          : (wrf + (long)(125 - it) * 131072 + kq * 16384 + t * 512 + lane * 8);
#pragma unroll
      for (int i = 0; i < 16; ++i) wbuf[i] = *(const half8*)(wb + i * 1024);
    }

    // ======== issue x prefetch for site it+1 (consumed after K-loop)
    float2 pxf;
    const bool haspx = (it + 1 < NIT) && (tid < 512);
    if (haspx) {
      const int row = tid >> 4, q = tid & 15;
      const int nsite = chain ? (253 - it) : (2 + it);
      pxf = *(const float2*)(x + ((long)(b0 + row) * 256 + nsite) * 32 + 2 * q);
    }

    // ======== LDS prework: zero P, preload state regs from Q, x-octets
    for (int i = tid; i < 32 * VPAD; i += 1024) P[i] = 0.f;

    half2v vsp[8];             // left: splatted v scalars, d in [8kq, 8kq+8)
    unsigned int roct[4][4];   // right: r octets (f16x2 x4) at e0 = 16c + 8h
    unsigned int xo[2][4];     // left: x octets per parity
    unsigned int xw0 = 0, xw1 = 0;  // right: packed x words for f = 4kq..4kq+3
    if (chain == 0) {
      const float* src = Q + m * VPAD + kq * 8;
#pragma unroll
      for (int qq = 0; qq < 4; ++qq) {
        const float2 f2 = *(const float2*)(src + 2 * qq);
        vsp[2 * qq] = splat2(f2.x);
        vsp[2 * qq + 1] = splat2(f2.y);
      }
#pragma unroll
      for (int p = 0; p < 2; ++p)
#pragma unroll
        for (int i = 0; i < 4; ++i) xo[p][i] = xsf[cb][p][lane][i];
    } else {
      const float* src = Q + m * VPAD + 8 * h;
#pragma unroll
      for (int c = 0; c < 4; ++c)
#pragma unroll
        for (int i = 0; i < 4; ++i) {
          const float2 f2 = *(const float2*)(src + 16 * c + 2 * i);
          roct[c][i] = pack2h(f2.x, f2.y);
        }
      xw0 = xplu[cb][m][2 * kq];
      xw1 = xplu[cb][m][2 * kq + 1];
    }
    LGKM_BARRIER();  // barrier1: P zeroed + Q reads done; W burst still flying

    // ======== compute: pure mulfrag + MFMA, counted vmcnt per wbuf use
    f32x16 acc = zero16();
    if (chain == 0) {
#pragma unroll
      for (int q = 0; q < 8; ++q) {
        half8 a0 = mulfrag(vsp[q], xo[0]);
        acc = MFMA32(a0, wbuf[2 * q], acc);
        half8 a1 = mulfrag(vsp[q], xo[1]);
        acc = MFMA32(a1, wbuf[2 * q + 1], acc);
      }
    } else {
#pragma unroll
      for (int q = 0; q < 4; ++q) {
        const half2v pw = __builtin_bit_cast(half2v, (q & 2) ? xw1 : xw0);
        const _Float16 xv = (q & 1) ? pw[1] : pw[0];
        half2v sp;
        sp[0] = xv;
        sp[1] = xv;
#pragma unroll
        for (int c = 0; c < 4; ++c) {
          half8 a = mulfrag(sp, roct[c]);
          acc = MFMA32(a, wbuf[4 * q + c], acc);
        }
      }
    }

    // ======== write prefetched x into the other buffer
    if (haspx) {
      const int row = tid >> 4, q = tid & 15;
      const unsigned int pk = pack2h(pxf.x, pxf.y);
      if (chain == 0)
        xsf[nb][q >> 3][((q >> 2) & 1) * 32 + row][q & 3] = pk;
      else
        xplu[nb][row][q] = pk;
    }

    // ======== epilogue: K-reduction across 8 kq-waves via LDS float atomics
#pragma unroll
    for (int gg = 0; gg < 16; ++gg) {
      const int g = (gg + 2 * kq) & 15;  // stagger start to avoid same-address pileup
      const int r = (g & 3) + ((g >> 2) << 3) + (h << 2);
      atomicAdd(&P[r * VPAD + t * 32 + m], acc[g]);
    }
    LGKM_BARRIER();  // barrier2: atomics + x-buffer write visible
  }

  // ---- store final state to workspace
  {
    const float* FB = vacc[(NIT - 1) & 1];
    float* dst = (chain ? wsR : wsV) + (long)b0 * 64;
    for (int i = tid; i < 2048; i += 1024) dst[i] = FB[(i >> 6) * VPAD + (i & 63)];
  }
}

// ---------------------------------------------------------------------------
// Label kernel: logits[b,o] = sum_e r_be * [ (v (x) x_label) @ Wlab ]_{b,(e,o)}
// 128 blocks x 32 rows x 1024 threads; wave: t = w&1, kq = w>>1 (K-eighth).
// ---------------------------------------------------------------------------
__launch_bounds__(1024, 4)
__global__ void label_kernel(const float* __restrict__ x,
                             const _Float16* __restrict__ wlabf,
                             const float* __restrict__ wsV, const float* __restrict__ wsR,
                             float* __restrict__ out) {
  __shared__ float vsh[32 * VPAD];
  __shared__ float rsh[32 * VPAD];
  __shared__ unsigned int xsf[2][64][4];
  __shared__ float lacc[32][17];

  const int tid = threadIdx.x, lane = tid & 63, wv = tid >> 6;
  const int t = wv & 1, kq = wv >> 1;
  const int m = lane & 31, h = lane >> 5;
  const long b0 = (long)blockIdx.x * 32;

  for (int i = tid; i < 2048; i += 1024) {
    vsh[(i >> 6) * VPAD + (i & 63)] = wsV[b0 * 64 + i];
    rsh[(i >> 6) * VPAD + (i & 63)] = wsR[b0 * 64 + i];
  }
  if (tid < 544) ((float*)lacc)[tid] = 0.f;
  if (tid < 512) {
    const int row = tid >> 4, q = tid & 15;
    const float2 f2 = *(const float2*)(x + ((b0 + row) * 256 + 128) * 32 + 2 * q);
    xsf[q >> 3][((q >> 2) & 1) * 32 + row][q & 3] = pack2h(f2.x, f2.y);
  }
  __syncthreads();

  half2v vsp[8];
  {
    const float* src = vsh + m * VPAD + kq * 8;
#pragma unroll
    for (int qq = 0; qq < 4; ++qq) {
      const float2 f2 = *(const float2*)(src + 2 * qq);
      vsp[2 * qq] = splat2(f2.x);
      vsp[2 * qq + 1] = splat2(f2.y);
    }
  }
  unsigned int xo[2][4];
#pragma unroll
  for (int p = 0; p < 2; ++p)
#pragma unroll
    for (int i = 0; i < 4; ++i) xo[p][i] = xsf[p][lane][i];

  float lg[16];
#pragma unroll
  for (int g = 0; g < 16; ++g) lg[g] = 0.f;

  // B addr (halves): s*16384 + t32*512 + lane*8, s = 16kq + 2q + p, t32 = 2g2 + t
  const _Float16* wb = wlabf + (long)kq * 16 * 16384 + t * 512 + lane * 8;
  for (int g2 = 0; g2 < 16; ++g2) {  // n-groups: one n-tile per wave each
    f32x16 acc = zero16();
    const _Float16* wg = wb + (long)g2 * 1024;
    half8 wbuf[8];
#pragma unroll
    for (int i = 0; i < 8; ++i) wbuf[i] = *(const half8*)(wg + (long)i * 16384);
#pragma unroll
    for (int q = 0; q < 4; ++q) {
      half8 a0 = mulfrag(vsp[q], xo[0]);
      acc = MFMA32(a0, wbuf[2 * q], acc);
      half8 a1 = mulfrag(vsp[q], xo[1]);
      acc = MFMA32(a1, wbuf[2 * q + 1], acc);
    }
#pragma unroll
    for (int i = 0; i < 8; ++i) wbuf[i] = *(const half8*)(wg + (long)(8 + i) * 16384);
#pragma unroll
    for (int q = 4; q < 8; ++q) {
      half8 a0 = mulfrag(vsp[q], xo[0]);
      acc = MFMA32(a0, wbuf[2 * (q - 4)], acc);
      half8 a1 = mulfrag(vsp[q], xo[1]);
      acc = MFMA32(a1, wbuf[2 * (q - 4) + 1], acc);
    }
    // fold n-tile into per-lane logit accs: n = (2g2+t)*32+m -> e = 4g2+2t+(m>>4), o = m&15
    const int e = g2 * 4 + t * 2 + (m >> 4);
#pragma unroll
    for (int g = 0; g < 16; ++g) {
      const int r = (g & 3) + ((g >> 2) << 3) + (h << 2);
      lg[g] += acc[g] * rsh[r * VPAD + e];
    }
  }
#pragma unroll
  for (int gg = 0; gg < 16; ++gg) {
    const int g = (gg + 2 * kq) & 15;
    const int r = (g & 3) + ((g >> 2) << 3) + (h << 2);
    atomicAdd(&lacc[r][m & 15], lg[g]);  // sums K-eighths AND e-halves
  }
  __syncthreads();
  if (tid < 512) out[b0 * 16 + tid] = lacc[tid >> 4][tid & 15];
}

extern "C" void kernel_launch(void* const* d_in, const int* in_sizes, int n_in,
                              void* d_out, int out_size, void* d_ws, size_t ws_size,
                              hipStream_t stream) {
  const float* x = (const float*)d_in[0];      // (4096,256,32)
  const float* w0 = (const float*)d_in[1];     // (32,64)
  const float* wl = (const float*)d_in[2];     // (127,64,32,64)
  const float* wlab = (const float*)d_in[3];   // (64,32,64,16)
  const float* wr = (const float*)d_in[4];     // (126,64,32,64)
  const float* wlast = (const float*)d_in[5];  // (64,32)

  char* ws = (char*)d_ws;
  _Float16* wlf = (_Float16*)(ws + WS_WLF);
  _Float16* wrf = (_Float16*)(ws + WS_WRF);
  _Float16* wlabf = (_Float16*)(ws + WS_WLAB);
  float* wsV = (float*)(ws + WS_V);
  float* wsR = (float*)(ws + WS_R);

  prep_kernel<<<2048, 256, 0, stream>>>(wl, wr, wlab, wlf, wrf, wlabf);
  chain_kernel<<<256, 1024, 0, stream>>>(x, w0, wlast, wlf, wrf, wsV, wsR);
  label_kernel<<<128, 1024, 0, stream>>>(x, wlabf, wsV, wsR, (float*)d_out);
}

// Round 4
// 3458.641 us; speedup vs baseline: 1.2153x; 1.2153x over previous
//
#include <hip/hip_runtime.h>

// MPS forward, MI355X/gfx950.
// B=4096 S=256 F=32 D=64 O=16, LABEL=128.
// Per-site GEMM v' = (v (x) x) @ W, K=(d,f)=2048, N=64, mfma_f32_32x32x16_f16.
// A synthesized in regs (splat * x-octet, v_pk_mul_f16); W pre-swizzled to MFMA
// fragment order in ws (fp16).
// v5 (= v4 hardened): W streamed via global_load_lds into a 4x32KB LDS phase
// rotation (K-sixteenth = 16 slices = 32KB per phase), 3 phases prefetched
// ahead (~48KB in flight per CU), counted s_waitcnt vmcnt(4) lgkmcnt(0) + raw
// s_barrier per phase (T3+T4; vmcnt never drained in the main loop).
// Fixes vs v4: (1) label grid back to 128 blocks; (2) staging is
// UNCONDITIONAL with clamped phase id (tail re-stages the final pair with
// identical bytes -> uniform 2-gll/phase vmcnt ledger, no lastsite peel);
// (3) lgkmcnt(0) folded into every phase wait (kills the ds_read-vs-gll
// buffer-overwrite race); (4) final vmcnt(0) drain before the state store.
// 16 waves: wave = (ks 0..7, t 0..1); per phase: 2 gll + 2 ds_read_b128 +
// 2 mulfrag + 2 MFMA. Left/right chains share one branch-free K-loop via
// unified splat/octet registers. K-reduction via LDS float atomics into
// ping-pong fp32 state. x double-buffered (reg prefetch, packed at epilogue).

typedef _Float16 half2v __attribute__((ext_vector_type(2)));
typedef _Float16 half8 __attribute__((ext_vector_type(8)));
typedef float f32x16 __attribute__((ext_vector_type(16)));
typedef unsigned int uint4v __attribute__((ext_vector_type(4)));

#define MFMA32(a, b, c) __builtin_amdgcn_mfma_f32_32x32x16_f16((a), (b), (c), 0, 0, 0)

#define VPAD 66  // fp32 state row stride (64 + 2 pad)

// workspace byte offsets (total 72,613,888 bytes required)
#define WS_WLF 0L
#define WS_WRF 33292288L
#define WS_WLAB 66322432L
#define WS_V 70516736L
#define WS_R 71565312L

__device__ __forceinline__ f32x16 zero16() {
  f32x16 z;
#pragma unroll
  for (int i = 0; i < 16; ++i) z[i] = 0.0f;
  return z;
}

__device__ __forceinline__ unsigned int pack2h(float a, float b) {
  half2v h;
  h[0] = (_Float16)a;
  h[1] = (_Float16)b;
  return __builtin_bit_cast(unsigned int, h);
}

__device__ __forceinline__ half2v splat2(float a) {
  _Float16 x = (_Float16)a;
  half2v h;
  h[0] = x;
  h[1] = x;
  return h;
}

// A-fragment synth: splat-scalar * f16-octet (4x v_pk_mul_f16)
__device__ __forceinline__ half8 mulfrag(const half2v s, const unsigned int* o) {
  uint4v t;
#pragma unroll
  for (int i = 0; i < 4; ++i) {
    half2v b = __builtin_bit_cast(half2v, o[i]);
    half2v p = s * b;
    t[i] = __builtin_bit_cast(unsigned int, p);
  }
  return __builtin_bit_cast(half8, t);
}

// async global->LDS, 16B per lane; LDS dest is wave-uniform base + lane*16
__device__ __forceinline__ void gll16(const _Float16* g, _Float16* l) {
  __builtin_amdgcn_global_load_lds(
      (const __attribute__((address_space(1))) void*)g,
      (__attribute__((address_space(3))) void*)l, 16, 0, 0);
}

// ---------------------------------------------------------------------------
// Prologue: convert W to fp16 in MFMA B-fragment order.
// Fragment id F = ((site*128 + s)*2 + t)*64 + lane  (chains)
//             F = (s*32 + t)*64 + lane              (label)
// value j of fragment: B[k = s*16 + (lane>>5)*8 + j][n = t*32 + (lane&31)]
// left/label: k=(d,f) -> d=k>>5, f=k&31 ; n=e (left) or n=(e*16+o) (label)
// right:      k=(f,e) -> f=k>>6, e=k&63 ; n=d
// ---------------------------------------------------------------------------
__global__ void prep_kernel(const float* __restrict__ wl, const float* __restrict__ wr,
                            const float* __restrict__ wlab,
                            _Float16* __restrict__ wlf, _Float16* __restrict__ wrf,
                            _Float16* __restrict__ wlabf) {
  const long t0 = (long)blockIdx.x * blockDim.x + threadIdx.x;
  const long stride = (long)gridDim.x * blockDim.x;
  const long NL = 127L * 128 * 2 * 64;
  const long NR = 126L * 128 * 2 * 64;
  const long NB = 128L * 32 * 64;

  for (long F = t0; F < NL; F += stride) {
    const int l = (int)(F & 63), t = (int)((F >> 6) & 1);
    const int s = (int)((F >> 7) & 127), site = (int)(F >> 14);
    const int k0 = s * 16 + ((l >> 5) << 3);
    const int d = k0 >> 5, f0 = k0 & 31, e = t * 32 + (l & 31);
    const float* src = wl + (((long)site * 64 + d) * 32 + f0) * 64 + e;
    half8 v;
#pragma unroll
    for (int j = 0; j < 8; ++j) v[j] = (_Float16)src[(long)j * 64];
    *(half8*)(wlf + F * 8) = v;
  }
  for (long F = t0; F < NR; F += stride) {
    const int l = (int)(F & 63), t = (int)((F >> 6) & 1);
    const int s = (int)((F >> 7) & 127), site = (int)(F >> 14);
    const int k0 = s * 16 + ((l >> 5) << 3);
    const int f = k0 >> 6, e0 = k0 & 63, d = t * 32 + (l & 31);
    const float* src = wr + (((long)site * 64 + d) * 32 + f) * 64 + e0;
    half8 v;
#pragma unroll
    for (int j = 0; j < 8; ++j) v[j] = (_Float16)src[j];
    *(half8*)(wrf + F * 8) = v;
  }
  for (long F = t0; F < NB; F += stride) {
    const int l = (int)(F & 63), t = (int)((F >> 6) & 31);
    const int s = (int)(F >> 11);
    const int k0 = s * 16 + ((l >> 5) << 3);
    const int d = k0 >> 5, f0 = k0 & 31;
    const int n = t * 32 + (l & 31);
    const int e = n >> 4, oo = n & 15;
    const float* src = wlab + (((long)d * 32 + f0) * 64 + e) * 16 + oo;
    half8 v;
#pragma unroll
    for (int j = 0; j < 8; ++j) v[j] = (_Float16)src[(long)j * 1024];
    *(half8*)(wlabf + F * 8) = v;
  }
}

// ---------------------------------------------------------------------------
// Chain kernel: blocks 0..127 = left chain, 128..255 = right chain; 32 rows
// each, 1024 threads = 16 waves. Wave: t = w&1 (N-tile), ks = w>>1.
// Phase p (K-sixteenth) covers slices s = 16p + {0..15}; wave (ks,t) computes
// slices 16p+2ks, 16p+2ks+1 at N-tile t. d = 8p+ks (left), f = 4p+(ks>>1)
// (right) are the per-phase splat scalars; x/r octets are phase-invariant.
// ---------------------------------------------------------------------------
__launch_bounds__(1024, 4)
__global__ void chain_kernel(const float* __restrict__ x, const float* __restrict__ w0,
                             const float* __restrict__ wlast,
                             const _Float16* __restrict__ wlf,
                             const _Float16* __restrict__ wrf,
                             float* __restrict__ wsV, float* __restrict__ wsR) {
  __shared__ __align__(16) _Float16 wstage[4][16384];  // 4 x 32KB W phase buffers
  __shared__ float vacc[2][32 * VPAD];                 // ping-pong fp32 state
  __shared__ unsigned int xsf[2][2][64][4];            // left: x octets, dbuf
  __shared__ unsigned int xplu[2][32][17];             // right: packed f16 x, dbuf

  const int tid = threadIdx.x;
  const int lane = tid & 63;
  const int wv = tid >> 6;   // 0..15
  const int t = wv & 1;      // N-tile
  const int ks = wv >> 1;    // slice-pair index 0..7
  const int m = lane & 31;
  const int h = lane >> 5;
  const int chain = blockIdx.x >> 7;  // 0 = left(v), 1 = right(r)
  const int b0 = (blockIdx.x & 127) * 32;
  const int NIT = chain ? 126 : 127;
  const int gmax = NIT * 8 - 1;

  // stage 2 chunks (1KB each) of global phase g into wstage[g&3].
  // g is CLAMPED to gmax: tail calls re-stage the final pair with identical
  // bytes (same src, same dst) -> benign, keeps the vmcnt ledger uniform.
  auto stage = [&](int g) {
    const int gc = (g <= gmax) ? g : gmax;
    const int st = gc >> 3, ph = gc & 7;
    const _Float16* base = chain ? (wrf + (long)(125 - st) * 131072)
                                 : (wlf + (long)st * 131072);
    const _Float16* gsrc = base + (long)ph * 16384 + (2 * wv) * 512 + lane * 8;
    _Float16* ldst = &wstage[gc & 3][(2 * wv) * 512];
    gll16(gsrc, ldst);
    gll16(gsrc + 512, ldst + 512);
  };

  // ---- init: x edge column into xinit (aliases wstage[0], used before glls)
  float* xinit = (float*)&wstage[0][0];  // [32][33]
  if (tid < 128) {
    const int row = tid >> 2, c8 = (tid & 3) * 8;
    const float* xp = x + ((long)(b0 + row) * 256 + (chain ? 255 : 0)) * 32 + c8;
    const float4 xa = ((const float4*)xp)[0];
    const float4 xb = ((const float4*)xp)[1];
    float* d = xinit + row * 33 + c8;
    d[0] = xa.x; d[1] = xa.y; d[2] = xa.z; d[3] = xa.w;
    d[4] = xb.x; d[5] = xb.y; d[6] = xb.z; d[7] = xb.w;
  }
  __syncthreads();
  // init state: v0 = x[:,0] @ W0  |  r0[d] = sum_f x[:,255][f]*Wlast[d][f]
  {
    const int row = tid >> 5, c = tid & 31;
    float a0 = 0.f, a1 = 0.f;
    if (chain == 0) {
#pragma unroll 8
      for (int f = 0; f < 32; ++f) {
        a0 += xinit[row * 33 + f] * w0[f * 64 + c];
        a1 += xinit[row * 33 + f] * w0[f * 64 + c + 32];
      }
    } else {
#pragma unroll 8
      for (int f = 0; f < 32; ++f) {
        a0 += xinit[row * 33 + f] * wlast[c * 32 + f];
        a1 += xinit[row * 33 + f] * wlast[(c + 32) * 32 + f];
      }
    }
    vacc[1][row * VPAD + c] = a0;
    vacc[1][row * VPAD + c + 32] = a1;
  }
  // stage x for first site into buffer 0
  if (tid < 512) {
    const int row = tid >> 4, q = tid & 15;
    const float2 f2 = *(const float2*)(x + ((long)(b0 + row) * 256 + (chain ? 254 : 1)) * 32 + 2 * q);
    const unsigned int pk = pack2h(f2.x, f2.y);
    if (chain == 0)
      xsf[0][q >> 3][((q >> 2) & 1) * 32 + row][q & 3] = pk;
    else
      xplu[0][row][q] = pk;
  }
  __syncthreads();  // full drain OK (no glls yet); publishes xinit-use end + x/state

  // issue W staging for site-0 phases 0,1,2 (FIFO: W0 W0 W1 W1 W2 W2)
  stage(0);
  stage(1);
  stage(2);

  for (int it = 0; it < NIT; ++it) {
    float* P = vacc[it & 1];               // this site's accumulator
    const float* Q = vacc[(it + 1) & 1];   // previous state
    const int cb = it & 1, nb = cb ^ 1;
    const int it8 = it * 8;

    // x prefetch for site it+1 (single vm load per thread; consumed at epilogue)
    float2 pxf;
    const bool haspx = (it + 1 < NIT) && (tid < 512);
    if (haspx) {
      const int row = tid >> 4, q = tid & 15;
      const int nsite = chain ? (253 - it) : (2 + it);
      pxf = *(const float2*)(x + ((long)(b0 + row) * 256 + nsite) * 32 + 2 * q);
    }

    // prework: zero P; unified splat/octet regs from Q and x buffers
    for (int i = tid; i < 32 * VPAD; i += 1024) P[i] = 0.f;

    half2v spl[8];             // left: v[m, 8p+ks] ; right: x[m, 4p+(ks>>1)]
    unsigned int oct2[2][4];   // left: x octets {f0=8h, 16+8h} ; right: r octets {e0, e0+16}
    if (chain == 0) {
#pragma unroll
      for (int p = 0; p < 8; ++p) spl[p] = splat2(Q[m * VPAD + 8 * p + ks]);
#pragma unroll
      for (int i = 0; i < 4; ++i) {
        oct2[0][i] = xsf[cb][0][lane][i];
        oct2[1][i] = xsf[cb][1][lane][i];
      }
    } else {
      const int kh = ks >> 1;
#pragma unroll
      for (int p = 0; p < 8; ++p) {
        const half2v pw = __builtin_bit_cast(half2v, xplu[cb][m][2 * p + (kh >> 1)]);
        const _Float16 xv = (kh & 1) ? pw[1] : pw[0];
        half2v sp; sp[0] = xv; sp[1] = xv;
        spl[p] = sp;
      }
      const int e0 = (ks & 1) * 32 + 8 * h;
#pragma unroll
      for (int c = 0; c < 2; ++c)
#pragma unroll
        for (int i = 0; i < 4; ++i) {
          const float2 f2 = *(const float2*)(Q + m * VPAD + e0 + 16 * c + 2 * i);
          oct2[c][i] = pack2h(f2.x, f2.y);
        }
    }
    asm volatile("s_waitcnt lgkmcnt(0)" ::: "memory");
    __builtin_amdgcn_s_barrier();  // barrier1: P zeroed, Q/x reads done; glls flying
    asm volatile("" ::: "memory");

    f32x16 acc = zero16();

    // 8 phases: wait(counted vm + full lgkm) -> barrier -> stage(p+3) -> compute(p)
#define PHASE(p)                                                               \
    {                                                                          \
      asm volatile("s_waitcnt vmcnt(4) lgkmcnt(0)" ::: "memory");              \
      __builtin_amdgcn_s_barrier();                                            \
      asm volatile("" ::: "memory");                                           \
      stage(it8 + (p) + 3);                                                    \
      {                                                                        \
        const _Float16* W =                                                    \
            &wstage[(p) & 3][0] + (4 * ks + t) * 512 + lane * 8;               \
        const half8 bA = *(const half8*)(W);                                   \
        const half8 bB = *(const half8*)(W + 1024);                            \
        const half8 aA = mulfrag(spl[(p)], oct2[0]);                          \
        const half8 aB = mulfrag(spl[(p)], oct2[1]);                          \
        acc = MFMA32(aA, bA, acc);                                             \
        acc = MFMA32(aB, bB, acc);                                             \
      }                                                                        \
    }

    PHASE(0) PHASE(1) PHASE(2) PHASE(3) PHASE(4) PHASE(5) PHASE(6) PHASE(7)
#undef PHASE

    // write prefetched x into the other buffer
    if (haspx) {
      const int row = tid >> 4, q = tid & 15;
      const unsigned int pk = pack2h(pxf.x, pxf.y);
      if (chain == 0)
        xsf[nb][q >> 3][((q >> 2) & 1) * 32 + row][q & 3] = pk;
      else
        xplu[nb][row][q] = pk;
    }

    // K-reduction across 8 ks-waves via LDS float atomics (ks-staggered)
#pragma unroll
    for (int gg = 0; gg < 16; ++gg) {
      const int g = (gg + 2 * ks) & 15;
      const int r = (g & 3) + ((g >> 2) << 3) + (h << 2);
      atomicAdd(&P[r * VPAD + t * 32 + m], acc[g]);
    }
    asm volatile("s_waitcnt lgkmcnt(0)" ::: "memory");
    __builtin_amdgcn_s_barrier();  // barrier2: atomics + x-buffer visible
    asm volatile("" ::: "memory");
  }

  // ---- drain remaining (duplicate-tail) glls, then store final state
  asm volatile("s_waitcnt vmcnt(0)" ::: "memory");
  {
    const float* FB = vacc[(NIT - 1) & 1];
    float* dst = (chain ? wsR : wsV) + (long)b0 * 64;
    for (int i = tid; i < 2048; i += 1024) dst[i] = FB[(i >> 6) * VPAD + (i & 63)];
  }
}

// ---------------------------------------------------------------------------
// Label kernel: logits[b,o] = sum_e r_be * [ (v (x) x_label) @ Wlab ]_{b,(e,o)}
// 128 blocks x 32 rows x 1024 threads; wave: t = w&1, kq = w>>1 (K-eighth).
// ---------------------------------------------------------------------------
__launch_bounds__(1024, 4)
__global__ void label_kernel(const float* __restrict__ x,
                             const _Float16* __restrict__ wlabf,
                             const float* __restrict__ wsV, const float* __restrict__ wsR,
                             float* __restrict__ out) {
  __shared__ float vsh[32 * VPAD];
  __shared__ float rsh[32 * VPAD];
  __shared__ unsigned int xsf[2][64][4];
  __shared__ float lacc[32][17];

  const int tid = threadIdx.x, lane = tid & 63, wv = tid >> 6;
  const int t = wv & 1, kq = wv >> 1;
  const int m = lane & 31, h = lane >> 5;
  const long b0 = (long)blockIdx.x * 32;

  for (int i = tid; i < 2048; i += 1024) {
    vsh[(i >> 6) * VPAD + (i & 63)] = wsV[b0 * 64 + i];
    rsh[(i >> 6) * VPAD + (i & 63)] = wsR[b0 * 64 + i];
  }
  if (tid < 544) ((float*)lacc)[tid] = 0.f;
  if (tid < 512) {
    const int row = tid >> 4, q = tid & 15;
    const float2 f2 = *(const float2*)(x + ((b0 + row) * 256 + 128) * 32 + 2 * q);
    xsf[q >> 3][((q >> 2) & 1) * 32 + row][q & 3] = pack2h(f2.x, f2.y);
  }
  __syncthreads();

  half2v vsp[8];
  {
    const float* src = vsh + m * VPAD + kq * 8;
#pragma unroll
    for (int qq = 0; qq < 4; ++qq) {
      const float2 f2 = *(const float2*)(src + 2 * qq);
      vsp[2 * qq] = splat2(f2.x);
      vsp[2 * qq + 1] = splat2(f2.y);
    }
  }
  unsigned int xo[2][4];
#pragma unroll
  for (int p = 0; p < 2; ++p)
#pragma unroll
    for (int i = 0; i < 4; ++i) xo[p][i] = xsf[p][lane][i];

  float lg[16];
#pragma unroll
  for (int g = 0; g < 16; ++g) lg[g] = 0.f;

  // B addr (halves): s*16384 + t32*512 + lane*8, s = 16kq + 2q + p, t32 = 2g2 + t
  const _Float16* wb = wlabf + (long)kq * 16 * 16384 + t * 512 + lane * 8;
  for (int g2 = 0; g2 < 16; ++g2) {  // n-groups: one n-tile per wave each
    f32x16 acc = zero16();
    const _Float16* wg = wb + (long)g2 * 1024;
    half8 wbuf[8];
#pragma unroll
    for (int i = 0; i < 8; ++i) wbuf[i] = *(const half8*)(wg + (long)i * 16384);
#pragma unroll
    for (int q = 0; q < 4; ++q) {
      half8 a0 = mulfrag(vsp[q], xo[0]);
      acc = MFMA32(a0, wbuf[2 * q], acc);
      half8 a1 = mulfrag(vsp[q], xo[1]);
      acc = MFMA32(a1, wbuf[2 * q + 1], acc);
    }
#pragma unroll
    for (int i = 0; i < 8; ++i) wbuf[i] = *(const half8*)(wg + (long)(8 + i) * 16384);
#pragma unroll
    for (int q = 4; q < 8; ++q) {
      half8 a0 = mulfrag(vsp[q], xo[0]);
      acc = MFMA32(a0, wbuf[2 * (q - 4)], acc);
      half8 a1 = mulfrag(vsp[q], xo[1]);
      acc = MFMA32(a1, wbuf[2 * (q - 4) + 1], acc);
    }
    // fold n-tile: n = (2g2+t)*32+m -> e = 4g2+2t+(m>>4), o = m&15
    const int e = g2 * 4 + t * 2 + (m >> 4);
#pragma unroll
    for (int g = 0; g < 16; ++g) {
      const int r = (g & 3) + ((g >> 2) << 3) + (h << 2);
      lg[g] += acc[g] * rsh[r * VPAD + e];
    }
  }
#pragma unroll
  for (int gg = 0; gg < 16; ++gg) {
    const int g = (gg + 2 * kq) & 15;
    const int r = (g & 3) + ((g >> 2) << 3) + (h << 2);
    atomicAdd(&lacc[r][m & 15], lg[g]);  // sums K-eighths AND e-halves
  }
  __syncthreads();
  if (tid < 512) out[b0 * 16 + tid] = lacc[tid >> 4][tid & 15];
}

extern "C" void kernel_launch(void* const* d_in, const int* in_sizes, int n_in,
                              void* d_out, int out_size, void* d_ws, size_t ws_size,
                              hipStream_t stream) {
  const float* x = (const float*)d_in[0];      // (4096,256,32)
  const float* w0 = (const float*)d_in[1];     // (32,64)
  const float* wl = (const float*)d_in[2];     // (127,64,32,64)
  const float* wlab = (const float*)d_in[3];   // (64,32,64,16)
  const float* wr = (const float*)d_in[4];     // (126,64,32,64)
  const float* wlast = (const float*)d_in[5];  // (64,32)

  char* ws = (char*)d_ws;
  _Float16* wlf = (_Float16*)(ws + WS_WLF);
  _Float16* wrf = (_Float16*)(ws + WS_WRF);
  _Float16* wlabf = (_Float16*)(ws + WS_WLAB);
  float* wsV = (float*)(ws + WS_V);
  float* wsR = (float*)(ws + WS_R);

  prep_kernel<<<2048, 256, 0, stream>>>(wl, wr, wlab, wlf, wrf, wlabf);
  chain_kernel<<<256, 1024, 0, stream>>>(x, w0, wlast, wlf, wrf, wsV, wsR);
  label_kernel<<<128, 1024, 0, stream>>>(x, wlabf, wsV, wsR, (float*)d_out);
}